// Round 5
// baseline (778.653 us; speedup 1.0000x reference)
//
#include <hip/hip_runtime.h>

typedef __bf16 bf16;
typedef __bf16 bf16x8 __attribute__((ext_vector_type(8)));
typedef float floatx4 __attribute__((ext_vector_type(4)));

#define MFMA(a, b, c) __builtin_amdgcn_mfma_f32_16x16x32_bf16((a), (b), (c), 0, 0, 0)

__device__ inline bf16x8 load8(const bf16* p) { return *(const bf16x8*)(p); }

// fp32 source: two float4 loads + convert to bf16x8 (RNE)
__device__ inline bf16x8 load8(const float* p) {
    const float4 u = *(const float4*)(p);
    const float4 v = *(const float4*)(p + 4);
    bf16x8 r;
    r[0] = (bf16)u.x; r[1] = (bf16)u.y; r[2] = (bf16)u.z; r[3] = (bf16)u.w;
    r[4] = (bf16)v.x; r[5] = (bf16)v.y; r[6] = (bf16)v.z; r[7] = (bf16)v.w;
    return r;
}

__device__ inline void store_c(bf16* p, float v) { *p = (bf16)v; }
__device__ inline void store_c(float* p, float v) { *p = v; }

// C[M,N] = A[M,K] @ W[N,K]^T + bias[N], fp32 accum.
// M=4096, N=1024, K=1024. Block = 4 waves, block tile 128x128, wave tile 64x64.
// If TR: write transposed-per-head layout T[h=n>>6][d=n&63][s=m] (S=4096).
// (MFMA layout validated vs VALU reference GEMM in round-3/4 A/B: bit-level agreement.)
template <typename TA, typename TC, bool TR>
__global__ __launch_bounds__(256) void gemm_bt(const TA* __restrict__ A,
                                               const float* __restrict__ W,
                                               const float* __restrict__ bias,
                                               TC* __restrict__ C) {
    const int K = 1024, N = 1024;
    const int wave = threadIdx.x >> 6;
    const int lane = threadIdx.x & 63;
    const int quad = lane >> 4, lo = lane & 15;
    const int bm = blockIdx.y * 128 + (wave >> 1) * 64;
    const int bn = blockIdx.x * 128 + (wave & 1) * 64;

    floatx4 acc[4][4] = {};

    for (int k0 = 0; k0 < K; k0 += 32) {
        bf16x8 a[4], b[4];
#pragma unroll
        for (int i = 0; i < 4; i++)
            a[i] = load8(A + (size_t)(bm + i * 16 + lo) * K + k0 + quad * 8);
#pragma unroll
        for (int j = 0; j < 4; j++)
            b[j] = load8(W + (size_t)(bn + j * 16 + lo) * K + k0 + quad * 8);
#pragma unroll
        for (int i = 0; i < 4; i++)
#pragma unroll
            for (int j = 0; j < 4; j++)
                acc[i][j] = MFMA(a[i], b[j], acc[i][j]);
    }

#pragma unroll
    for (int i = 0; i < 4; i++) {
#pragma unroll
        for (int j = 0; j < 4; j++) {
#pragma unroll
            for (int r = 0; r < 4; r++) {
                const int m = bm + i * 16 + quad * 4 + r;
                const int n = bn + j * 16 + lo;
                const float v = acc[i][j][r] + bias[n];
                if (!TR) {
                    store_c(C + (size_t)m * N + n, v);
                } else {
                    // T[h][d][s]: h=n>>6, d=n&63, s=m
                    store_c(C + (size_t)(n >> 6) * (64 * 4096) + (size_t)(n & 63) * 4096 + m, v);
                }
            }
        }
    }
}

// Flash attention: one wave per (head, 16-query tile). S=4096, d_k=64, 16 heads.
// Q, Kmat: [4096][1024] bf16 (head h = cols h*64..h*64+63). Vt: [16][64][4096].
// O out: [4096][1024] bf16.
// (Validated vs attn_valu in round-2/3 A/B: bit-level agreement.)
__global__ __launch_bounds__(64) void flash_attn(const bf16* __restrict__ Q,
                                                 const bf16* __restrict__ Kmat,
                                                 const bf16* __restrict__ Vt,
                                                 bf16* __restrict__ O) {
    __shared__ bf16 Plds[16][32];  // P tile: [q_local][key_local]

    const int lane = threadIdx.x;
    const int quad = lane >> 4, lo = lane & 15;
    const int h = blockIdx.x;   // 16
    const int qt = blockIdx.y;  // 256
    const int DM = 1024;

    // Q A-fragments (held for the whole kernel): A[m=lo][k=quad*8+j], two d-halves
    const bf16* qb = Q + (size_t)(qt * 16 + lo) * DM + h * 64 + quad * 8;
    const bf16x8 aQ0 = load8(qb);
    const bf16x8 aQ1 = load8(qb + 32);

    floatx4 Oacc[4] = {};
    float mr[4], lr[4];
#pragma unroll
    for (int r = 0; r < 4; r++) { mr[r] = -1e30f; lr[r] = 0.0f; }

    const bf16* Kb = Kmat + h * 64 + quad * 8;                           // + key*DM
    const bf16* Vb = Vt + (size_t)h * 64 * 4096 + lo * 4096 + quad * 8;  // + nt*16*4096 + kb

    for (int kb = 0; kb < 4096; kb += 32) {
        // ---- QK^T: S-tile [16 q x 32 keys] as two C-frags ----
        const bf16* k0p = Kb + (size_t)(kb + lo) * DM;
        const bf16* k1p = Kb + (size_t)(kb + 16 + lo) * DM;
        floatx4 s0 = {}, s1 = {};
        s0 = MFMA(aQ0, load8(k0p), s0);
        s0 = MFMA(aQ1, load8(k0p + 32), s0);
        s1 = MFMA(aQ0, load8(k1p), s1);
        s1 = MFMA(aQ1, load8(k1p + 32), s1);

        // ---- online softmax (per C-frag row q = quad*4 + r, cols across lane&15) ----
#pragma unroll
        for (int r = 0; r < 4; r++) {
            const float x0 = s0[r] * 0.125f;
            const float x1 = s1[r] * 0.125f;
            float mx = fmaxf(x0, x1);
#pragma unroll
            for (int off = 1; off < 16; off <<= 1) mx = fmaxf(mx, __shfl_xor(mx, off, 64));
            const float mnew = fmaxf(mr[r], mx);
            const float alpha = __expf(mr[r] - mnew);
            const float p0 = __expf(x0 - mnew);
            const float p1 = __expf(x1 - mnew);
            float rs = p0 + p1;
#pragma unroll
            for (int off = 1; off < 16; off <<= 1) rs += __shfl_xor(rs, off, 64);
            lr[r] = lr[r] * alpha + rs;
            mr[r] = mnew;
#pragma unroll
            for (int nt = 0; nt < 4; nt++) Oacc[nt][r] *= alpha;
            Plds[quad * 4 + r][lo] = (bf16)p0;
            Plds[quad * 4 + r][16 + lo] = (bf16)p1;
        }
        __syncthreads();
        // P in A-layout: A[m=lo][k=quad*8+j]
        const bf16x8 aP = load8(&Plds[lo][quad * 8]);
        __syncthreads();

        // ---- PV: O[16 q x 64 d] += P[16x32] @ V[32 keys x 64 d] ----
#pragma unroll
        for (int nt = 0; nt < 4; nt++) {
            const bf16x8 bV = load8(Vb + (size_t)nt * 16 * 4096 + kb);
            Oacc[nt] = MFMA(aP, bV, Oacc[nt]);
        }
    }

#pragma unroll
    for (int r = 0; r < 4; r++) {
        const float inv = 1.0f / lr[r];
#pragma unroll
        for (int nt = 0; nt < 4; nt++) {
            O[(size_t)(qt * 16 + quad * 4 + r) * DM + h * 64 + nt * 16 + lo] =
                (bf16)(Oacc[nt][r] * inv);
        }
    }
}

extern "C" void kernel_launch(void* const* d_in, const int* in_sizes, int n_in,
                              void* d_out, int out_size, void* d_ws, size_t ws_size,
                              hipStream_t stream) {
    const float* query = (const float*)d_in[0];
    const float* key_i = (const float*)d_in[1];
    const float* value = (const float*)d_in[2];
    const float* Wq = (const float*)d_in[3];
    const float* bq = (const float*)d_in[4];
    const float* Wk = (const float*)d_in[5];
    const float* bk = (const float*)d_in[6];
    const float* Wv = (const float*)d_in[7];
    const float* bv = (const float*)d_in[8];
    const float* Wo = (const float*)d_in[9];
    const float* bo = (const float*)d_in[10];

    bf16* ws = (bf16*)d_ws;
    const size_t SZ = (size_t)4096 * 1024;
    bf16* Q = ws;            // [4096][1024]
    bf16* K = ws + SZ;       // [4096][1024]
    bf16* Vt = ws + 2 * SZ;  // [16][64][4096]
    bf16* O = ws + 3 * SZ;   // [4096][1024]

    dim3 gblk(256), ggrid(8, 32);  // N/128 x M/128
    gemm_bt<float, bf16, false><<<ggrid, gblk, 0, stream>>>(query, Wq, bq, Q);
    gemm_bt<float, bf16, false><<<ggrid, gblk, 0, stream>>>(key_i, Wk, bk, K);
    gemm_bt<float, bf16, true><<<ggrid, gblk, 0, stream>>>(value, Wv, bv, Vt);

    flash_attn<<<dim3(16, 256), 64, 0, stream>>>(Q, K, Vt, O);

    // d_out is FP32 (reference output dtype is float32) — the round-0..4 bug.
    gemm_bt<bf16, float, false><<<ggrid, gblk, 0, stream>>>(O, Wo, bo, (float*)d_out);
}